// Round 5
// baseline (1008.695 us; speedup 1.0000x reference)
//
#include <hip/hip_runtime.h>
#include <hip/hip_bf16.h>

typedef __hip_bfloat16 bf16;
typedef __attribute__((ext_vector_type(8))) short short8v;
typedef __attribute__((ext_vector_type(4))) float f32x4;

__device__ __forceinline__ float b2f(bf16 v){ return __bfloat162float(v); }
__device__ __forceinline__ bf16 f2b(float v){ return __float2bfloat16(v); }
__device__ __forceinline__ float softplus_f(float x){ return (x > 15.f) ? x : __logf(1.f + __expf(x)); }
__device__ __forceinline__ float sigmoid_f(float x){ return 1.f / (1.f + __expf(-x)); }

// ---------------- embedding: fea[n,d] = sum_k A[n,k] * W_emb[d,k] ----------------
__global__ __launch_bounds__(256) void k_embed(const float* __restrict__ A, const float* __restrict__ W,
                                               float* __restrict__ fea){
  __shared__ float Wl[92][64];
  __shared__ float Al[64][92];
  int t = threadIdx.x;
  int base = blockIdx.x * 64;
  for (int i = t; i < 92*64; i += 256){ int d = i / 92, k = i - d*92; Wl[k][d] = W[d*92 + k]; }
  for (int i = t; i < 64*92; i += 256){ int a = i / 92, k = i - a*92; Al[a][k] = A[(size_t)(base+a)*92 + k]; }
  __syncthreads();
  int d = t & 63, slot = t >> 6;
  for (int a = slot; a < 64; a += 4){
    float acc = 0.f;
    #pragma unroll 4
    for (int k = 0; k < 92; k++) acc += Al[a][k] * Wl[k][d];
    fea[(size_t)(base+a)*64 + d] = acc;
  }
}

// ---------------- P[n, c] = fea[n,:] . W_self/W_nbr columns ----------------
__global__ __launch_bounds__(256) void k_proj(const float* __restrict__ fea, const float* __restrict__ W,
                                              float* __restrict__ P){
  __shared__ float Fl[64][64];
  int t = threadIdx.x, base = blockIdx.x * 64;
  int c = t, cc = c & 127;
  const float* wrow = W + (size_t)cc*169 + ((c < 128) ? 0 : 64);
  float wreg[64];
  #pragma unroll
  for (int d = 0; d < 64; d++) wreg[d] = wrow[d];
  for (int i = t; i < 4096; i += 256){ int a = i >> 6, d = i & 63; Fl[a][d] = fea[(size_t)(base+a)*64 + d]; }
  __syncthreads();
  for (int a = 0; a < 64; a++){
    float acc = 0.f;
    #pragma unroll
    for (int db = 0; db < 16; db++){
      float4 fv = *(const float4*)&Fl[a][db*4];
      acc += fv.x*wreg[db*4] + fv.y*wreg[db*4+1] + fv.z*wreg[db*4+2] + fv.w*wreg[db*4+3];
    }
    P[(size_t)(base+a)*256 + c] = acc;
  }
}

// ---------------- gate via MFMA + LDS-staged P gathers ----------------
// Block: 256 rows (4 tiles of 64). Per tile: stage E rows + neighbor-P rows (bf16) + self-P rows
// into LDS with coalesced loads; epilogue reads LDS only. W B-frags live in registers.
__global__ __launch_bounds__(256) void k_gmm(const float* __restrict__ P, const float* __restrict__ nbrF,
    const int* __restrict__ idx, const float* __restrict__ W, const float* __restrict__ bg,
    bf16* __restrict__ gated, float* __restrict__ psum, float* __restrict__ psq){
  __shared__ bf16 El[64][72];
  __shared__ bf16 Pn[64][136];
  __shared__ float Psl[7][132];
  __shared__ float red_s[4][128], red_q[4][128];
  int t = threadIdx.x, L = t & 63, w = t >> 6;

  // W fragments (B-operand) into registers: 8 tc-tiles x 2 K-halves
  short8v wf0[8], wf1[8];
  {
    int cr = L & 15;
    int kb = (L >> 4) * 8;
    #pragma unroll
    for (int tc = 0; tc < 8; tc++){
      int cc = tc*16 + cr;
      bf16 t0[8], t1[8];
      #pragma unroll
      for (int j = 0; j < 8; j++){
        int k1 = 32 + kb + j;
        t0[j] = f2b(W[(size_t)cc*169 + 128 + kb + j]);                  // k<32 always valid (<41)
        t1[j] = f2b(k1 < 41 ? W[(size_t)cc*169 + 128 + k1] : 0.f);
      }
      wf0[tc] = *(const short8v*)t0;
      wf1[tc] = *(const short8v*)t1;
    }
  }
  float bbr[8];
  #pragma unroll
  for (int tc = 0; tc < 8; tc++) bbr[tc] = bg[tc*16 + (L & 15)];

  float acc_s[8], acc_q[8];
  #pragma unroll
  for (int tc = 0; tc < 8; tc++){ acc_s[tc] = 0.f; acc_q[tc] = 0.f; }

  int rbase = blockIdx.x * 256;
  for (int rt = 0; rt < 4; rt++){
    int row0 = rbase + rt*64;
    int a0 = row0 / 12;
    __syncthreads();   // prev-tile readers done
    // stage E rows (zero-pad K 41->64)
    for (int i = t; i < 64*64; i += 256){ int rr = i >> 6, e = i & 63;
      El[rr][e] = f2b(e < 41 ? nbrF[(size_t)(row0+rr)*41 + e] : 0.f); }
    // stage neighbor-P rows as bf16: row rr's 512B read contiguously by 32 lanes
    for (int i = t; i < 64*32; i += 256){
      int rr = i >> 5, q = i & 31;
      int j = idx[row0 + rr];
      float4 v = *(const float4*)&P[(size_t)j*256 + 128 + q*4];
      bf16 tmp[4] = {f2b(v.x), f2b(v.y), f2b(v.z), f2b(v.w)};
      *(uint2*)&Pn[rr][q*4] = *(const uint2*)tmp;
    }
    // stage self-P rows (atoms a0..a0+6)
    for (int i = t; i < 896; i += 256){
      int ar = i >> 7, c = i & 127;
      int aa = a0 + ar; if (aa > 24575) aa = 24575;
      Psl[ar][c] = P[(size_t)aa*256 + c];
    }
    __syncthreads();

    short8v av0 = *(const short8v*)&El[w*16 + (L&15)][(L>>4)*8];
    short8v av1 = *(const short8v*)&El[w*16 + (L&15)][(L>>4)*8 + 32];
    int rloc = w*16 + (L>>4)*4;
    int al[4];
    #pragma unroll
    for (int r = 0; r < 4; r++) al[r] = (row0 + rloc + r)/12 - a0;

    #pragma unroll
    for (int tc = 0; tc < 8; tc++){
      f32x4 acc = (f32x4){0.f,0.f,0.f,0.f};
      acc = __builtin_amdgcn_mfma_f32_16x16x32_bf16(av0, wf0[tc], acc, 0, 0, 0);
      acc = __builtin_amdgcn_mfma_f32_16x16x32_bf16(av1, wf1[tc], acc, 0, 0, 0);
      int c = tc*16 + (L&15);
      float ps_ = 0.f, pq_ = 0.f;
      #pragma unroll
      for (int r = 0; r < 4; r++){
        int rr = rloc + r;
        float v = acc[r] + Psl[al[r]][c] + b2f(Pn[rr][c]) + bbr[tc];
        gated[(size_t)(row0+rr)*128 + c] = f2b(v);
        ps_ += v; pq_ += v*v;
      }
      acc_s[tc] += ps_; acc_q[tc] += pq_;
    }
  }
  #pragma unroll
  for (int tc = 0; tc < 8; tc++){
    float v = acc_s[tc]; v += __shfl_xor(v, 16); v += __shfl_xor(v, 32);
    float u = acc_q[tc]; u += __shfl_xor(u, 16); u += __shfl_xor(u, 32);
    if (L < 16){ red_s[w][tc*16 + L] = v; red_q[w][tc*16 + L] = u; }
  }
  __syncthreads();
  if (t < 128){
    psum[blockIdx.x*128 + t] = red_s[0][t] + red_s[1][t] + red_s[2][t] + red_s[3][t];
    psq [blockIdx.x*128 + t] = red_q[0][t] + red_q[1][t] + red_q[2][t] + red_q[3][t];
  }
}

__global__ __launch_bounds__(1024) void k_fin1(const float* __restrict__ ps, const float* __restrict__ pq,
    const float* __restrict__ g, const float* __restrict__ be, float* __restrict__ scale, float* __restrict__ shift){
  __shared__ float rs[1024], rq[1024];
  int t = threadIdx.x, c = t & 127, gi = t >> 7;
  float s = 0.f, q = 0.f;
  for (int b = gi; b < 1152; b += 8){ s += ps[b*128 + c]; q += pq[b*128 + c]; }
  rs[t] = s; rq[t] = q; __syncthreads();
  if (t < 128){
    float S = 0.f, Q = 0.f;
    #pragma unroll
    for (int gg = 0; gg < 8; gg++){ S += rs[gg*128 + t]; Q += rq[gg*128 + t]; }
    float cnt = 294912.0f;
    float mu = S / cnt;
    float var = Q / cnt - mu*mu;
    float sc = rsqrtf(var + 1e-5f) * g[t];
    scale[t] = sc;
    shift[t] = be[t] - mu * sc;
  }
}

// ---------------- pool: vectorized (short8) normalize + sigmoid*softplus + sum over M ----------------
// 256 threads = 32 atoms x 8 channel-blocks. Lane owns 8 contiguous channels (16B loads).
__global__ __launch_bounds__(256) void k_pool(const bf16* __restrict__ gated, const float* __restrict__ scale,
    const float* __restrict__ shift, float* __restrict__ summed, float* __restrict__ psum, float* __restrict__ psq){
  __shared__ float sc[128], sh[128];
  __shared__ float sb[32][65], qb[32][65];
  int t = threadIdx.x;
  if (t < 128){ sc[t] = scale[t]; sh[t] = shift[t]; }
  __syncthreads();
  int nl = t >> 3, jb = t & 7;
  int n = blockIdx.x*32 + nl;
  const bf16* gp = gated + (size_t)n*1536 + jb*8;
  float sc1r[8], sh1r[8], sc2r[8], sh2r[8];
  #pragma unroll
  for (int k = 0; k < 8; k++){
    int d = jb*8 + k;
    sc1r[k] = sc[d]; sh1r[k] = sh[d]; sc2r[k] = sc[64+d]; sh2r[k] = sh[64+d];
  }
  float acc[8];
  #pragma unroll
  for (int k = 0; k < 8; k++) acc[k] = 0.f;
  #pragma unroll
  for (int m = 0; m < 12; m++){
    short8v fv = *(const short8v*)(gp + m*128);
    short8v cv = *(const short8v*)(gp + m*128 + 64);
    #pragma unroll
    for (int k = 0; k < 8; k++){
      bf16 fb, cb;
      *(short*)&fb = fv[k]; *(short*)&cb = cv[k];
      float y1 = b2f(fb) * sc1r[k] + sh1r[k];
      float y2 = b2f(cb) * sc2r[k] + sh2r[k];
      acc[k] += sigmoid_f(y1) * softplus_f(y2);
    }
  }
  float* sp = &summed[(size_t)n*64 + jb*8];
  *(float4*)(sp+0) = make_float4(acc[0], acc[1], acc[2], acc[3]);
  *(float4*)(sp+4) = make_float4(acc[4], acc[5], acc[6], acc[7]);
  #pragma unroll
  for (int k = 0; k < 8; k++){ sb[nl][jb*8+k] = acc[k]; qb[nl][jb*8+k] = acc[k]*acc[k]; }
  __syncthreads();
  if (t < 64){
    float S = 0.f, Q = 0.f;
    #pragma unroll 4
    for (int nn = 0; nn < 32; nn++){ S += sb[nn][t]; Q += qb[nn][t]; }
    psum[blockIdx.x*64 + t] = S;
    psq [blockIdx.x*64 + t] = Q;
  }
}

__global__ __launch_bounds__(1024) void k_fin2(const float* __restrict__ ps, const float* __restrict__ pq,
    const float* __restrict__ g, const float* __restrict__ be, float* __restrict__ scale, float* __restrict__ shift){
  __shared__ float rs[1024], rq[1024];
  int t = threadIdx.x, c = t & 63, gi = t >> 6;
  float s = 0.f, q = 0.f;
  for (int b = gi; b < 768; b += 16){ s += ps[b*64 + c]; q += pq[b*64 + c]; }
  rs[t] = s; rq[t] = q; __syncthreads();
  if (t < 64){
    float S = 0.f, Q = 0.f;
    #pragma unroll
    for (int gg = 0; gg < 16; gg++){ S += rs[gg*64 + t]; Q += rq[gg*64 + t]; }
    float cnt = 24576.0f;
    float mu = S / cnt;
    float var = Q / cnt - mu*mu;
    float sc = rsqrtf(var + 1e-5f) * g[t];
    scale[t] = sc;
    shift[t] = be[t] - mu * sc;
  }
}

__global__ __launch_bounds__(256) void k_update(const float* __restrict__ fea, const float* __restrict__ summed,
    const float* __restrict__ sc2, const float* __restrict__ sh2, float* __restrict__ out){
  int i = blockIdx.x*256 + threadIdx.x;
  int d = i & 63;
  float x = fea[i] + summed[i]*sc2[d] + sh2[d];
  out[i] = softplus_f(x);
}

// ================= decode, stage 1: Zfrag[b][k] = W_k @ bt^T in MFMA-fragment order =================
__global__ __launch_bounds__(256) void k_zfill(const float* __restrict__ fea, const int* __restrict__ cidx,
    const float* __restrict__ Wadj, const float* __restrict__ Wedge, bf16* __restrict__ Zfrag){
  __shared__ bf16 Wd[64][72];
  __shared__ bf16 btb[48][72];
  int bx = blockIdx.x;
  int b = bx / 11, k = bx - b*11;
  const float* Wk = (k < 6) ? (Wadj + (size_t)k*4096) : (Wedge + (size_t)(k-6)*4096);
  int t = threadIdx.x, L = t & 63, w = t >> 6;
  const int* ci = cidx + b*48;
  for (int i = t; i < 4096; i += 256) Wd[i>>6][i&63] = f2b(Wk[i]);
  for (int i = t; i < 3072; i += 256){ int r = i>>6, d = i&63; btb[r][d] = f2b(fea[(size_t)ci[r]*64 + d]); }
  __syncthreads();
  bf16* Zb = Zfrag + (size_t)b*33792 + (size_t)k*3072;
  short8v av0 = *(const short8v*)&Wd[w*16 + (L&15)][(L>>4)*8];
  short8v av1 = *(const short8v*)&Wd[w*16 + (L&15)][(L>>4)*8 + 32];
  int s = L >> 4;
  int d0 = w*16 + s*4;
  int dc = d0 >> 5, sub = (d0 >> 3) & 3, off = d0 & 7;
  #pragma unroll
  for (int nc = 0; nc < 3; nc++){
    short8v bv0 = *(const short8v*)&btb[nc*16 + (L&15)][(L>>4)*8];
    short8v bv1 = *(const short8v*)&btb[nc*16 + (L&15)][(L>>4)*8 + 32];
    f32x4 z = (f32x4){0.f,0.f,0.f,0.f};
    z = __builtin_amdgcn_mfma_f32_16x16x32_bf16(av0, bv0, z, 0, 0, 0);
    z = __builtin_amdgcn_mfma_f32_16x16x32_bf16(av1, bv1, z, 0, 0, 0);
    bf16 zp[4];
    #pragma unroll
    for (int r = 0; r < 4; r++) zp[r] = f2b(z[r]);
    *(uint2*)&Zb[(size_t)((nc*2 + dc)*64 + sub*16 + (L&15))*8 + off] = *(const uint2*)zp;
  }
}

__global__ __launch_bounds__(256) void k_prep_atom(const float* __restrict__ Watom, bf16* __restrict__ Waf){
  int t = threadIdx.x;
  for (int i = t; i < 768; i += 256){
    int oc = i >> 7, rem = i & 127, dc = rem >> 6, L = rem & 63;
    int o = oc*16 + (L & 15);
    int dbase = (L >> 4)*8 + dc*32;
    bf16 tmp[8];
    #pragma unroll
    for (int j = 0; j < 8; j++) tmp[j] = f2b(o < 92 ? Watom[(size_t)o*64 + dbase + j] : 0.f);
    *(uint4*)&Waf[(size_t)i * 8] = *(const uint4*)tmp;
  }
}

// ================= decode, stage 2: pair scores + fc + log_softmax + atom head =================
__global__ __launch_bounds__(256) void k_pair(const float* __restrict__ fea, const int* __restrict__ cidx,
    const bf16* __restrict__ Zfrag, const bf16* __restrict__ Waf,
    const float* __restrict__ badj, const float* __restrict__ Wfc1, const float* __restrict__ bfc1,
    const float* __restrict__ bedge, const float* __restrict__ Wfc2, const float* __restrict__ bfc2,
    const float* __restrict__ batom, float* __restrict__ out){
  __shared__ float cst[84];
  int t = threadIdx.x, L = t & 63, w = t >> 6;
  int bx = blockIdx.x, b = bx / 3, mr = bx - b*3;
  if (t < 36) cst[t] = Wfc1[t];
  else if (t < 42) cst[t] = bfc1[t-36];
  else if (t < 48) cst[t] = badj[t-42];
  else if (t < 73) cst[t] = Wfc2[t-48];
  else if (t < 78) cst[t] = bfc2[t-73];
  else if (t < 83) cst[t] = bedge[t-78];
  int arow = cidx[b*48 + mr*16 + (L & 15)];
  const float* fr = fea + (size_t)arow*64 + (L >> 4)*8;
  float fa[16];
  *(float4*)(fa+0)  = *(const float4*)(fr+0);
  *(float4*)(fa+4)  = *(const float4*)(fr+4);
  *(float4*)(fa+8)  = *(const float4*)(fr+32);
  *(float4*)(fa+12) = *(const float4*)(fr+36);
  bf16 ab[16];
  #pragma unroll
  for (int j = 0; j < 16; j++) ab[j] = f2b(fa[j]);
  short8v av0 = *(const short8v*)&ab[0];
  short8v av1 = *(const short8v*)&ab[8];
  __syncthreads();

  if (w < 3){
    const bf16* Zb = Zfrag + (size_t)b*33792 + (size_t)w*1024;
    f32x4 acc[11];
    #pragma unroll
    for (int k = 0; k < 11; k++){
      const bf16* zp = Zb + (size_t)k*3072;
      short8v bv0 = *(const short8v*)&zp[(size_t)L*8];
      short8v bv1 = *(const short8v*)&zp[512 + (size_t)L*8];
      f32x4 a = (f32x4){0.f,0.f,0.f,0.f};
      a = __builtin_amdgcn_mfma_f32_16x16x32_bf16(av0, bv0, a, 0, 0, 0);
      a = __builtin_amdgcn_mfma_f32_16x16x32_bf16(av1, bv1, a, 0, 0, 0);
      acc[k] = a;
    }
    size_t obase = (size_t)b * 13824;
    size_t fbase = 9338880ull + (size_t)b * 11520;
    int n = w*16 + (L & 15);
    #pragma unroll
    for (int r = 0; r < 4; r++){
      int m = mr*16 + (L >> 4)*4 + r;
      float sv[6];
      #pragma unroll
      for (int k = 0; k < 6; k++) sv[k] = acc[k][r] + cst[42 + k];
      float v[6]; float mx = -1e30f;
      #pragma unroll
      for (int i2 = 0; i2 < 6; i2++){
        float a = cst[36 + i2];
        #pragma unroll
        for (int j2 = 0; j2 < 6; j2++) a += cst[i2*6 + j2] * sv[j2];
        v[i2] = a; mx = fmaxf(mx, a);
      }
      float lse = 0.f;
      #pragma unroll
      for (int i2 = 0; i2 < 6; i2++) lse += __expf(v[i2] - mx);
      lse = mx + __logf(lse);
      size_t po = obase + (size_t)(m*48 + n)*6;
      #pragma unroll
      for (int i2 = 0; i2 < 6; i2++) out[po + i2] = v[i2] - lse;
      float sf[5];
      #pragma unroll
      for (int k = 0; k < 5; k++) sf[k] = acc[6 + k][r] + cst[78 + k];
      size_t pf = fbase + (size_t)(m*48 + n)*5;
      #pragma unroll
      for (int i2 = 0; i2 < 5; i2++){
        float a = cst[73 + i2];
        #pragma unroll
        for (int j2 = 0; j2 < 5; j2++) a += cst[48 + i2*5 + j2] * sf[j2];
        out[pf + i2] = a;
      }
    }
  } else {
    size_t abase = 7077888ull + (size_t)b * 4416;
    #pragma unroll
    for (int oc = 0; oc < 6; oc++){
      short8v bv0 = *(const short8v*)&Waf[(size_t)((oc*2 + 0)*64 + L)*8];
      short8v bv1 = *(const short8v*)&Waf[(size_t)((oc*2 + 1)*64 + L)*8];
      f32x4 a = (f32x4){0.f,0.f,0.f,0.f};
      a = __builtin_amdgcn_mfma_f32_16x16x32_bf16(av0, bv0, a, 0, 0, 0);
      a = __builtin_amdgcn_mfma_f32_16x16x32_bf16(av1, bv1, a, 0, 0, 0);
      int o = oc*16 + (L & 15);
      if (o < 92){
        float bb2 = batom[o];
        #pragma unroll
        for (int r = 0; r < 4; r++){
          int m = mr*16 + (L >> 4)*4 + r;
          out[abase + (size_t)m*92 + o] = a[r] + bb2;
        }
      }
    }
  }
}

extern "C" void kernel_launch(void* const* d_in, const int* in_sizes, int n_in,
                              void* d_out, int out_size, void* d_ws, size_t ws_size,
                              hipStream_t stream) {
  const float* atom_fea = (const float*)d_in[0];
  const float* nbr_fea  = (const float*)d_in[1];
  const int*   nbr_idx  = (const int*)d_in[2];
  const int*   cidx     = (const int*)d_in[3];
  const float* W_emb    = (const float*)d_in[4];
  const float* W_full   = (const float*)d_in[5];
  const float* b_full   = (const float*)d_in[6];
  const float* g1       = (const float*)d_in[7];
  const float* be1      = (const float*)d_in[8];
  const float* g2       = (const float*)d_in[9];
  const float* be2      = (const float*)d_in[10];
  const float* W_adj    = (const float*)d_in[11];
  const float* b_adj    = (const float*)d_in[12];
  const float* W_fc1    = (const float*)d_in[13];
  const float* b_fc1    = (const float*)d_in[14];
  const float* W_edge   = (const float*)d_in[15];
  const float* b_edge   = (const float*)d_in[16];
  const float* W_fc2    = (const float*)d_in[17];
  const float* b_fc2    = (const float*)d_in[18];
  const float* W_atom   = (const float*)d_in[19];
  const float* b_atom   = (const float*)d_in[20];

  char* ws = (char*)d_ws;
  float* feaA   = (float*)(ws);                  // 6,291,456
  float* feaB   = (float*)(ws + 6291456);        // 6,291,456
  float* P      = (float*)(ws + 12582912);       // 25,165,824
  float* summed = (float*)(ws + 37748736);       // 6,291,456
  float* p1     = (float*)(ws + 44040192);       // 589,824 (1152 x 128)
  float* p1q    = (float*)(ws + 44630016);       // 589,824
  float* p2     = (float*)(ws + 45219840);       // 262,144 (768 x 64 used)
  float* p2q    = (float*)(ws + 45481984);       // 262,144
  float* sc1    = (float*)(ws + 45744128);
  float* sh1    = (float*)(ws + 45744640);
  float* sc2    = (float*)(ws + 45745152);
  float* sh2    = (float*)(ws + 45745408);
  bf16*  gated  = (bf16*)(ws + 45745664);        // 75,497,472
  bf16*  Zfrag  = (bf16*)(ws + 45745664);        // 34,603,008 — reuses gated (dead by decode)
  bf16*  Waf    = (bf16*)(ws + 80348672);        // 12,288
  float* out    = (float*)d_out;

  k_embed<<<384, 256, 0, stream>>>(atom_fea, W_emb, feaA);

  float* cur = feaA; float* nxt = feaB;
  for (int l = 0; l < 3; l++){
    const float* Wl = W_full + (size_t)l * 128 * 169;
    k_proj<<<384, 256, 0, stream>>>(cur, Wl, P);
    k_gmm<<<1152, 256, 0, stream>>>(P, nbr_fea, nbr_idx, Wl, b_full + l*128, gated, p1, p1q);
    k_fin1<<<1, 1024, 0, stream>>>(p1, p1q, g1 + l*128, be1 + l*128, sc1, sh1);
    k_pool<<<768, 256, 0, stream>>>(gated, sc1, sh1, summed, p2, p2q);
    k_fin2<<<1, 1024, 0, stream>>>(p2, p2q, g2 + l*64, be2 + l*64, sc2, sh2);
    k_update<<<6144, 256, 0, stream>>>(cur, summed, sc2, sh2, nxt);
    float* tmp = cur; cur = nxt; nxt = tmp;
  }

  k_prep_atom<<<1, 256, 0, stream>>>(W_atom, Waf);
  k_zfill<<<5632, 256, 0, stream>>>(cur, cidx, W_adj, W_edge, Zfrag);
  k_pair<<<1536, 256, 0, stream>>>(cur, cidx, Zfrag, Waf, b_adj, W_fc1, b_fc1,
                                   b_edge, W_fc2, b_fc2, b_atom, out);
}

// Round 6
// 700.676 us; speedup vs baseline: 1.4396x; 1.4396x over previous
//
#include <hip/hip_runtime.h>
#include <hip/hip_bf16.h>

typedef __hip_bfloat16 bf16;
typedef __attribute__((ext_vector_type(8))) short short8v;
typedef __attribute__((ext_vector_type(4))) float f32x4;

__device__ __forceinline__ float b2f(bf16 v){ return __bfloat162float(v); }
__device__ __forceinline__ bf16 f2b(float v){ return __float2bfloat16(v); }
__device__ __forceinline__ float softplus_f(float x){ return (x > 15.f) ? x : __logf(1.f + __expf(x)); }
__device__ __forceinline__ float sigmoid_f(float x){ return 1.f / (1.f + __expf(-x)); }

// ---------------- embedding: fea[n,d] = sum_k A[n,k] * W_emb[d,k] ----------------
__global__ __launch_bounds__(256) void k_embed(const float* __restrict__ A, const float* __restrict__ W,
                                               float* __restrict__ fea){
  __shared__ float Wl[92][64];
  __shared__ float Al[64][92];
  int t = threadIdx.x;
  int base = blockIdx.x * 64;
  for (int i = t; i < 92*64; i += 256){ int d = i / 92, k = i - d*92; Wl[k][d] = W[d*92 + k]; }
  for (int i = t; i < 64*92; i += 256){ int a = i / 92, k = i - a*92; Al[a][k] = A[(size_t)(base+a)*92 + k]; }
  __syncthreads();
  int d = t & 63, slot = t >> 6;
  for (int a = slot; a < 64; a += 4){
    float acc = 0.f;
    #pragma unroll 4
    for (int k = 0; k < 92; k++) acc += Al[a][k] * Wl[k][d];
    fea[(size_t)(base+a)*64 + d] = acc;
  }
}

// ---------------- P[n, c] = fea[n,:] . W_self/W_nbr columns ----------------
__global__ __launch_bounds__(256) void k_proj(const float* __restrict__ fea, const float* __restrict__ W,
                                              float* __restrict__ P){
  __shared__ float Fl[64][64];
  int t = threadIdx.x, base = blockIdx.x * 64;
  int c = t, cc = c & 127;
  const float* wrow = W + (size_t)cc*169 + ((c < 128) ? 0 : 64);
  float wreg[64];
  #pragma unroll
  for (int d = 0; d < 64; d++) wreg[d] = wrow[d];
  for (int i = t; i < 4096; i += 256){ int a = i >> 6, d = i & 63; Fl[a][d] = fea[(size_t)(base+a)*64 + d]; }
  __syncthreads();
  for (int a = 0; a < 64; a++){
    float acc = 0.f;
    #pragma unroll
    for (int db = 0; db < 16; db++){
      float4 fv = *(const float4*)&Fl[a][db*4];
      acc += fv.x*wreg[db*4] + fv.y*wreg[db*4+1] + fv.z*wreg[db*4+2] + fv.w*wreg[db*4+3];
    }
    P[(size_t)(base+a)*256 + c] = acc;
  }
}

// ---------------- gate (round-3 proven version): P_self + P_nbr[idx] + nbr_fea.W_e + b ----------------
__global__ __launch_bounds__(256) void k_gate(const float* __restrict__ P, const float* __restrict__ nbrF,
    const int* __restrict__ idx, const float* __restrict__ W, const float* __restrict__ bg,
    bf16* __restrict__ gated, float* __restrict__ psum, float* __restrict__ psq){
  __shared__ float nf[24][44];
  __shared__ int jrow[24];
  __shared__ float red[256];
  int t = threadIdx.x;
  int slot = t >> 7, c = t & 127;
  float wreg[41];
  #pragma unroll
  for (int e = 0; e < 41; e++) wreg[e] = W[(size_t)c*169 + 128 + e];
  float bv = bg[c];
  float s = 0.f, q = 0.f;
  int rbase = blockIdx.x * 288;
  for (int st = 0; st < 12; st++){
    int row0 = rbase + st*24;
    __syncthreads();
    for (int i = t; i < 24*41; i += 256){ int rr = i / 41, e = i - rr*41; nf[rr][e] = nbrF[(size_t)(row0+rr)*41 + e]; }
    if (t < 24) jrow[t] = idx[row0 + t];
    __syncthreads();
    int a = row0/12 + slot;
    float ps = P[(size_t)a*256 + c] + bv;
    #pragma unroll
    for (int m = 0; m < 12; m++){
      int rr = slot*12 + m;
      int j = jrow[rr];
      float acc = ps + P[(size_t)j*256 + 128 + c];
      #pragma unroll
      for (int eb = 0; eb < 10; eb++){
        float4 nv = *(const float4*)&nf[rr][eb*4];
        acc += nv.x*wreg[eb*4] + nv.y*wreg[eb*4+1] + nv.z*wreg[eb*4+2] + nv.w*wreg[eb*4+3];
      }
      acc += nf[rr][40] * wreg[40];
      gated[(size_t)(row0+rr)*128 + c] = f2b(acc);
      s += acc; q += acc*acc;
    }
  }
  red[t] = s; __syncthreads();
  if (t < 128) psum[blockIdx.x*128 + t] = red[t] + red[t+128];
  __syncthreads(); red[t] = q; __syncthreads();
  if (t < 128) psq[blockIdx.x*128 + t] = red[t] + red[t+128];
}

__global__ __launch_bounds__(1024) void k_fin1(const float* __restrict__ ps, const float* __restrict__ pq,
    const float* __restrict__ g, const float* __restrict__ be, float* __restrict__ scale, float* __restrict__ shift){
  __shared__ float rs[1024], rq[1024];
  int t = threadIdx.x, c = t & 127, gi = t >> 7;
  float s = 0.f, q = 0.f;
  for (int b = gi; b < 1024; b += 8){ s += ps[b*128 + c]; q += pq[b*128 + c]; }
  rs[t] = s; rq[t] = q; __syncthreads();
  if (t < 128){
    float S = 0.f, Q = 0.f;
    #pragma unroll
    for (int gg = 0; gg < 8; gg++){ S += rs[gg*128 + t]; Q += rq[gg*128 + t]; }
    float cnt = 294912.0f;
    float mu = S / cnt;
    float var = Q / cnt - mu*mu;
    float sc = rsqrtf(var + 1e-5f) * g[t];
    scale[t] = sc;
    shift[t] = be[t] - mu * sc;
  }
}

// ---------------- pool: vectorized (short8) normalize + sigmoid*softplus + sum over M ----------------
__global__ __launch_bounds__(256) void k_pool(const bf16* __restrict__ gated, const float* __restrict__ scale,
    const float* __restrict__ shift, float* __restrict__ summed, float* __restrict__ psum, float* __restrict__ psq){
  __shared__ float sc[128], sh[128];
  __shared__ float sb[32][65], qb[32][65];
  int t = threadIdx.x;
  if (t < 128){ sc[t] = scale[t]; sh[t] = shift[t]; }
  __syncthreads();
  int nl = t >> 3, jb = t & 7;
  int n = blockIdx.x*32 + nl;
  const bf16* gp = gated + (size_t)n*1536 + jb*8;
  float sc1r[8], sh1r[8], sc2r[8], sh2r[8];
  #pragma unroll
  for (int k = 0; k < 8; k++){
    int d = jb*8 + k;
    sc1r[k] = sc[d]; sh1r[k] = sh[d]; sc2r[k] = sc[64+d]; sh2r[k] = sh[64+d];
  }
  float acc[8];
  #pragma unroll
  for (int k = 0; k < 8; k++) acc[k] = 0.f;
  #pragma unroll
  for (int m = 0; m < 12; m++){
    short8v fv = *(const short8v*)(gp + m*128);
    short8v cv = *(const short8v*)(gp + m*128 + 64);
    #pragma unroll
    for (int k = 0; k < 8; k++){
      bf16 fb, cb;
      *(short*)&fb = fv[k]; *(short*)&cb = cv[k];
      float y1 = b2f(fb) * sc1r[k] + sh1r[k];
      float y2 = b2f(cb) * sc2r[k] + sh2r[k];
      acc[k] += sigmoid_f(y1) * softplus_f(y2);
    }
  }
  float* sp = &summed[(size_t)n*64 + jb*8];
  *(float4*)(sp+0) = make_float4(acc[0], acc[1], acc[2], acc[3]);
  *(float4*)(sp+4) = make_float4(acc[4], acc[5], acc[6], acc[7]);
  #pragma unroll
  for (int k = 0; k < 8; k++){ sb[nl][jb*8+k] = acc[k]; qb[nl][jb*8+k] = acc[k]*acc[k]; }
  __syncthreads();
  if (t < 64){
    float S = 0.f, Q = 0.f;
    #pragma unroll 4
    for (int nn = 0; nn < 32; nn++){ S += sb[nn][t]; Q += qb[nn][t]; }
    psum[blockIdx.x*64 + t] = S;
    psq [blockIdx.x*64 + t] = Q;
  }
}

__global__ __launch_bounds__(1024) void k_fin2(const float* __restrict__ ps, const float* __restrict__ pq,
    const float* __restrict__ g, const float* __restrict__ be, float* __restrict__ scale, float* __restrict__ shift){
  __shared__ float rs[1024], rq[1024];
  int t = threadIdx.x, c = t & 63, gi = t >> 6;
  float s = 0.f, q = 0.f;
  for (int b = gi; b < 768; b += 16){ s += ps[b*64 + c]; q += pq[b*64 + c]; }
  rs[t] = s; rq[t] = q; __syncthreads();
  if (t < 64){
    float S = 0.f, Q = 0.f;
    #pragma unroll
    for (int gg = 0; gg < 16; gg++){ S += rs[gg*64 + t]; Q += rq[gg*64 + t]; }
    float cnt = 24576.0f;
    float mu = S / cnt;
    float var = Q / cnt - mu*mu;
    float sc = rsqrtf(var + 1e-5f) * g[t];
    scale[t] = sc;
    shift[t] = be[t] - mu * sc;
  }
}

__global__ __launch_bounds__(256) void k_update(const float* __restrict__ fea, const float* __restrict__ summed,
    const float* __restrict__ sc2, const float* __restrict__ sh2, float* __restrict__ out){
  int i = blockIdx.x*256 + threadIdx.x;
  int d = i & 63;
  float x = fea[i] + summed[i]*sc2[d] + sh2[d];
  out[i] = softplus_f(x);
}

// ================= decode, stage 1: Zfrag[b][k] = W_k @ bt^T in MFMA-fragment order =================
__global__ __launch_bounds__(256) void k_zfill(const float* __restrict__ fea, const int* __restrict__ cidx,
    const float* __restrict__ Wadj, const float* __restrict__ Wedge, bf16* __restrict__ Zfrag){
  __shared__ bf16 Wd[64][72];
  __shared__ bf16 btb[48][72];
  int bx = blockIdx.x;
  int b = bx / 11, k = bx - b*11;
  const float* Wk = (k < 6) ? (Wadj + (size_t)k*4096) : (Wedge + (size_t)(k-6)*4096);
  int t = threadIdx.x, L = t & 63, w = t >> 6;
  const int* ci = cidx + b*48;
  for (int i = t; i < 4096; i += 256) Wd[i>>6][i&63] = f2b(Wk[i]);
  for (int i = t; i < 3072; i += 256){ int r = i>>6, d = i&63; btb[r][d] = f2b(fea[(size_t)ci[r]*64 + d]); }
  __syncthreads();
  bf16* Zb = Zfrag + (size_t)b*33792 + (size_t)k*3072;
  short8v av0 = *(const short8v*)&Wd[w*16 + (L&15)][(L>>4)*8];
  short8v av1 = *(const short8v*)&Wd[w*16 + (L&15)][(L>>4)*8 + 32];
  int s = L >> 4;
  int d0 = w*16 + s*4;
  int dc = d0 >> 5, sub = (d0 >> 3) & 3, off = d0 & 7;
  #pragma unroll
  for (int nc = 0; nc < 3; nc++){
    short8v bv0 = *(const short8v*)&btb[nc*16 + (L&15)][(L>>4)*8];
    short8v bv1 = *(const short8v*)&btb[nc*16 + (L&15)][(L>>4)*8 + 32];
    f32x4 z = (f32x4){0.f,0.f,0.f,0.f};
    z = __builtin_amdgcn_mfma_f32_16x16x32_bf16(av0, bv0, z, 0, 0, 0);
    z = __builtin_amdgcn_mfma_f32_16x16x32_bf16(av1, bv1, z, 0, 0, 0);
    bf16 zp[4];
    #pragma unroll
    for (int r = 0; r < 4; r++) zp[r] = f2b(z[r]);
    *(uint2*)&Zb[(size_t)((nc*2 + dc)*64 + sub*16 + (L&15))*8 + off] = *(const uint2*)zp;
  }
}

__global__ __launch_bounds__(256) void k_prep_atom(const float* __restrict__ Watom, bf16* __restrict__ Waf){
  int t = threadIdx.x;
  for (int i = t; i < 768; i += 256){
    int oc = i >> 7, rem = i & 127, dc = rem >> 6, L = rem & 63;
    int o = oc*16 + (L & 15);
    int dbase = (L >> 4)*8 + dc*32;
    bf16 tmp[8];
    #pragma unroll
    for (int j = 0; j < 8; j++) tmp[j] = f2b(o < 92 ? Watom[(size_t)o*64 + dbase + j] : 0.f);
    *(uint4*)&Waf[(size_t)i * 8] = *(const uint4*)tmp;
  }
}

// ================= decode, stage 2: pair scores + fc + log_softmax + atom head =================
__global__ __launch_bounds__(256) void k_pair(const float* __restrict__ fea, const int* __restrict__ cidx,
    const bf16* __restrict__ Zfrag, const bf16* __restrict__ Waf,
    const float* __restrict__ badj, const float* __restrict__ Wfc1, const float* __restrict__ bfc1,
    const float* __restrict__ bedge, const float* __restrict__ Wfc2, const float* __restrict__ bfc2,
    const float* __restrict__ batom, float* __restrict__ out){
  __shared__ float cst[84];
  int t = threadIdx.x, L = t & 63, w = t >> 6;
  int bx = blockIdx.x, b = bx / 3, mr = bx - b*3;
  if (t < 36) cst[t] = Wfc1[t];
  else if (t < 42) cst[t] = bfc1[t-36];
  else if (t < 48) cst[t] = badj[t-42];
  else if (t < 73) cst[t] = Wfc2[t-48];
  else if (t < 78) cst[t] = bfc2[t-73];
  else if (t < 83) cst[t] = bedge[t-78];
  int arow = cidx[b*48 + mr*16 + (L & 15)];
  const float* fr = fea + (size_t)arow*64 + (L >> 4)*8;
  float fa[16];
  *(float4*)(fa+0)  = *(const float4*)(fr+0);
  *(float4*)(fa+4)  = *(const float4*)(fr+4);
  *(float4*)(fa+8)  = *(const float4*)(fr+32);
  *(float4*)(fa+12) = *(const float4*)(fr+36);
  bf16 ab[16];
  #pragma unroll
  for (int j = 0; j < 16; j++) ab[j] = f2b(fa[j]);
  short8v av0 = *(const short8v*)&ab[0];
  short8v av1 = *(const short8v*)&ab[8];
  __syncthreads();

  if (w < 3){
    const bf16* Zb = Zfrag + (size_t)b*33792 + (size_t)w*1024;
    f32x4 acc[11];
    #pragma unroll
    for (int k = 0; k < 11; k++){
      const bf16* zp = Zb + (size_t)k*3072;
      short8v bv0 = *(const short8v*)&zp[(size_t)L*8];
      short8v bv1 = *(const short8v*)&zp[512 + (size_t)L*8];
      f32x4 a = (f32x4){0.f,0.f,0.f,0.f};
      a = __builtin_amdgcn_mfma_f32_16x16x32_bf16(av0, bv0, a, 0, 0, 0);
      a = __builtin_amdgcn_mfma_f32_16x16x32_bf16(av1, bv1, a, 0, 0, 0);
      acc[k] = a;
    }
    size_t obase = (size_t)b * 13824;
    size_t fbase = 9338880ull + (size_t)b * 11520;
    int n = w*16 + (L & 15);
    #pragma unroll
    for (int r = 0; r < 4; r++){
      int m = mr*16 + (L >> 4)*4 + r;
      float sv[6];
      #pragma unroll
      for (int k = 0; k < 6; k++) sv[k] = acc[k][r] + cst[42 + k];
      float v[6]; float mx = -1e30f;
      #pragma unroll
      for (int i2 = 0; i2 < 6; i2++){
        float a = cst[36 + i2];
        #pragma unroll
        for (int j2 = 0; j2 < 6; j2++) a += cst[i2*6 + j2] * sv[j2];
        v[i2] = a; mx = fmaxf(mx, a);
      }
      float lse = 0.f;
      #pragma unroll
      for (int i2 = 0; i2 < 6; i2++) lse += __expf(v[i2] - mx);
      lse = mx + __logf(lse);
      size_t po = obase + (size_t)(m*48 + n)*6;
      #pragma unroll
      for (int i2 = 0; i2 < 6; i2++) out[po + i2] = v[i2] - lse;
      float sf[5];
      #pragma unroll
      for (int k = 0; k < 5; k++) sf[k] = acc[6 + k][r] + cst[78 + k];
      size_t pf = fbase + (size_t)(m*48 + n)*5;
      #pragma unroll
      for (int i2 = 0; i2 < 5; i2++){
        float a = cst[73 + i2];
        #pragma unroll
        for (int j2 = 0; j2 < 5; j2++) a += cst[48 + i2*5 + j2] * sf[j2];
        out[pf + i2] = a;
      }
    }
  } else {
    size_t abase = 7077888ull + (size_t)b * 4416;
    #pragma unroll
    for (int oc = 0; oc < 6; oc++){
      short8v bv0 = *(const short8v*)&Waf[(size_t)((oc*2 + 0)*64 + L)*8];
      short8v bv1 = *(const short8v*)&Waf[(size_t)((oc*2 + 1)*64 + L)*8];
      f32x4 a = (f32x4){0.f,0.f,0.f,0.f};
      a = __builtin_amdgcn_mfma_f32_16x16x32_bf16(av0, bv0, a, 0, 0, 0);
      a = __builtin_amdgcn_mfma_f32_16x16x32_bf16(av1, bv1, a, 0, 0, 0);
      int o = oc*16 + (L & 15);
      if (o < 92){
        float bb2 = batom[o];
        #pragma unroll
        for (int r = 0; r < 4; r++){
          int m = mr*16 + (L >> 4)*4 + r;
          out[abase + (size_t)m*92 + o] = a[r] + bb2;
        }
      }
    }
  }
}

extern "C" void kernel_launch(void* const* d_in, const int* in_sizes, int n_in,
                              void* d_out, int out_size, void* d_ws, size_t ws_size,
                              hipStream_t stream) {
  const float* atom_fea = (const float*)d_in[0];
  const float* nbr_fea  = (const float*)d_in[1];
  const int*   nbr_idx  = (const int*)d_in[2];
  const int*   cidx     = (const int*)d_in[3];
  const float* W_emb    = (const float*)d_in[4];
  const float* W_full   = (const float*)d_in[5];
  const float* b_full   = (const float*)d_in[6];
  const float* g1       = (const float*)d_in[7];
  const float* be1      = (const float*)d_in[8];
  const float* g2       = (const float*)d_in[9];
  const float* be2      = (const float*)d_in[10];
  const float* W_adj    = (const float*)d_in[11];
  const float* b_adj    = (const float*)d_in[12];
  const float* W_fc1    = (const float*)d_in[13];
  const float* b_fc1    = (const float*)d_in[14];
  const float* W_edge   = (const float*)d_in[15];
  const float* b_edge   = (const float*)d_in[16];
  const float* W_fc2    = (const float*)d_in[17];
  const float* b_fc2    = (const float*)d_in[18];
  const float* W_atom   = (const float*)d_in[19];
  const float* b_atom   = (const float*)d_in[20];

  char* ws = (char*)d_ws;
  float* feaA   = (float*)(ws);                  // 6,291,456
  float* feaB   = (float*)(ws + 6291456);        // 6,291,456
  float* P      = (float*)(ws + 12582912);       // 25,165,824
  float* summed = (float*)(ws + 37748736);       // 6,291,456
  float* p1     = (float*)(ws + 44040192);       // 524,288 (1024 x 128)
  float* p1q    = (float*)(ws + 44630016);       // 524,288
  float* p2     = (float*)(ws + 45219840);       // 196,608 (768 x 64)
  float* p2q    = (float*)(ws + 45481984);       // 196,608
  float* sc1    = (float*)(ws + 45744128);
  float* sh1    = (float*)(ws + 45744640);
  float* sc2    = (float*)(ws + 45745152);
  float* sh2    = (float*)(ws + 45745408);
  bf16*  gated  = (bf16*)(ws + 45745664);        // 75,497,472
  bf16*  Zfrag  = (bf16*)(ws + 45745664);        // 34,603,008 — reuses gated (dead by decode)
  bf16*  Waf    = (bf16*)(ws + 80348672);        // 12,288
  float* out    = (float*)d_out;

  k_embed<<<384, 256, 0, stream>>>(atom_fea, W_emb, feaA);

  float* cur = feaA; float* nxt = feaB;
  for (int l = 0; l < 3; l++){
    const float* Wl = W_full + (size_t)l * 128 * 169;
    k_proj<<<384, 256, 0, stream>>>(cur, Wl, P);
    k_gate<<<1024, 256, 0, stream>>>(P, nbr_fea, nbr_idx, Wl, b_full + l*128, gated, p1, p1q);
    k_fin1<<<1, 1024, 0, stream>>>(p1, p1q, g1 + l*128, be1 + l*128, sc1, sh1);
    k_pool<<<768, 256, 0, stream>>>(gated, sc1, sh1, summed, p2, p2q);
    k_fin2<<<1, 1024, 0, stream>>>(p2, p2q, g2 + l*64, be2 + l*64, sc2, sh2);
    k_update<<<6144, 256, 0, stream>>>(cur, summed, sc2, sh2, nxt);
    float* tmp = cur; cur = nxt; nxt = tmp;
  }

  k_prep_atom<<<1, 256, 0, stream>>>(W_atom, Waf);
  k_zfill<<<5632, 256, 0, stream>>>(cur, cidx, W_adj, W_edge, Zfrag);
  k_pair<<<1536, 256, 0, stream>>>(cur, cidx, Zfrag, Waf, b_adj, W_fc1, b_fc1,
                                   b_edge, W_fc2, b_fc2, b_atom, out);
}